// Round 10
// baseline (215.479 us; speedup 1.0000x reference)
//
#include <hip/hip_runtime.h>
#include <math.h>

#ifndef __has_builtin
#define __has_builtin(x) 0
#endif

#if __has_builtin(__builtin_amdgcn_rcpf)
#define FAST_RCP(x) __builtin_amdgcn_rcpf(x)
#else
#define FAST_RCP(x) (1.0f / (x))
#endif

#if __has_builtin(__builtin_amdgcn_exp2f)
#define FAST_EXP2(x) __builtin_amdgcn_exp2f(x)
#else
#define FAST_EXP2(x) exp2f(x)
#endif

typedef _Float16 half8 __attribute__((ext_vector_type(8)));
typedef _Float16 half2v __attribute__((ext_vector_type(2)));
typedef float f32x4 __attribute__((ext_vector_type(4)));
typedef float f32x2 __attribute__((ext_vector_type(2)));

constexpr int T_STEPS  = 180;
constexpr int I_DIM    = 7;
constexpr int XLEN     = T_STEPS * I_DIM;  // 1260
constexpr int HDIM     = 64;
constexpr int BT       = 16;    // batch tile per block
constexpr int BSTRIDE  = 104;   // halfs per B row: 208 B (96 data + 8 pad)

// Block = 512 threads = 8 waves, grid 512 -> 2 independent blocks/CU
// (anti-phased barriers; measured best vs 1 block/CU and vs x-preload).
// Per step GEMM: gates[256 x 16] = W_aug[256 x 96(f16)] . v[96 x 16(f16)],
//   v = [x_t(7), 1, h_{t-1}(64), pad].
// A rows packed UNIT-MAJOR, adjacent-unit remap: lane (q,n15) of wave w's
// tile pt holds i,f,g,o of unit 8w+2q+pt -> thread's 2 cells are adjacent
// units {8w+2q,+1}: ONE packed b32 h write per step.
// Activation scales folded into weights (exp2-ready pre-activations).
// Cell pair: shared-denominator + cross-cell merged rcp (10 exp2 + 2 rcp
// per thread-step). Upper-only clamps (negative exp2 underflow is exact).
// x path: spread across waves -- wave w (w<7) owns x column i=w for all 16
// batch rows (lanes 0..15), 2-step-deep register pipeline; near-identical
// instruction streams across waves minimize barrier skew.
__global__ __launch_bounds__(512, 4) void lstm_mfma_kernel(
    const float* __restrict__ x,
    const float* __restrict__ W_ih,
    const float* __restrict__ W_hh,
    const float* __restrict__ b_ih,
    const float* __restrict__ b_hh,
    const float* __restrict__ W_fc,
    const float* __restrict__ b_fc,
    float* __restrict__ out) {
    __shared__ alignas(16) _Float16 Blds[2][BT][BSTRIDE];
    __shared__ alignas(16) float hlds[BT][HDIM + 4];   // fp32 h_T for epilogue

    const int tid  = (int)threadIdx.x;
    const int w    = tid >> 6;    // wave 0..7
    const int lane = tid & 63;
    const int q    = lane >> 4;   // quad 0..3
    const int n15  = lane & 15;   // batch col within tile
    const long bbase = (long)blockIdx.x * BT;

    // ---- A fragments, scale-folded, in registers for all 180 steps ----
    half8 afrag[2][3];
#pragma unroll
    for (int pt = 0; pt < 2; ++pt) {
        const int rq   = n15 >> 2;            // row-quad of this packed row
        const int gate = n15 & 3;
        const int unit = 8 * w + 2 * rq + pt; // adjacent-unit remap
        const int grow = gate * HDIM + unit;  // row in PyTorch [4H, *] params
        const float scl = (gate == 2) ? 2.88539008177792681472f
                                      : -1.44269504088896340736f;
#pragma unroll
        for (int kc = 0; kc < 3; ++kc) {
#pragma unroll
            for (int j = 0; j < 8; ++j) {
                const int k = kc * 32 + q * 8 + j;
                float v;
                if (k < I_DIM)            v = W_ih[grow * I_DIM + k];
                else if (k == I_DIM)      v = b_ih[grow] + b_hh[grow];
                else if (k < 8 + HDIM)    v = W_hh[grow * HDIM + (k - 8)];
                else                      v = 0.0f;
                afrag[pt][kc][j] = (_Float16)(scl * v);
            }
        }
    }

    // ---- init both B buffers: bias col = 1, h = 0, pad = 0; buf0 x = x_0 ----
    for (int idx = tid; idx < 2 * BT * BSTRIDE; idx += 512) {
        const int buf = idx / (BT * BSTRIDE);
        const int rem = idx % (BT * BSTRIDE);
        const int n = rem / BSTRIDE, k = rem % BSTRIDE;
        float v = 0.0f;
        if (k == I_DIM)                 v = 1.0f;
        else if (k < I_DIM && buf == 0) v = x[(bbase + n) * XLEN + k];
        Blds[buf][n][k] = (_Float16)v;
    }
    __syncthreads();

    // cell ownership: units u0 = 8w+2q, u0+1 (adjacent), batch n15
    const int u0 = 8 * w + 2 * q;

    // hoisted LDS pointers (loop-invariant)
    const _Float16* const rb0 = &Blds[0][n15][q * 8];
    const _Float16* const rb1 = &Blds[1][n15][q * 8];
    half2v* const hw0 = (half2v*)&Blds[0][n15][8 + u0];
    half2v* const hw1 = (half2v*)&Blds[1][n15][8 + u0];

    // x duty spread across waves: wave w (w<7) owns x column i=w for batch
    // rows n = lane (lanes 0..15). One 4B load + one b16 store per step.
    const int xn = lane;                       // batch row 0..15
    const int xi = (w < 7) ? w : 0;            // x column (wave 7 inactive)
    const bool xact = (lane < 16) && (w < 7);
    const float* const xcol = x + (bbase + xn) * XLEN + xi;
    _Float16* const xw0 = &Blds[0][xn][xi];
    _Float16* const xw1 = &Blds[1][xn][xi];

    // 2-deep x pipeline
    float xA = xact ? xcol[1 * I_DIM] : 0.0f;   // x_1 (written during t=0)
    float xB = xact ? xcol[2 * I_DIM] : 0.0f;   // x_2 (written during t=1)

    float c0 = 0.0f, c1 = 0.0f, h0 = 0.0f, h1 = 0.0f;

    // Cell pair, merged rcps. acc = {i',f',g',o'} exp2-ready.
    //   P=(1+A)(E+1), Q=1+F; c' = (cP + (E-1)Q) * rcp(P0Q0*P1Q1) * (other PQ)
    //   d=(1+O)(C+1);        h  = (C-1) * rcp(d0*d1) * (other d)
    // E and C upper-clamped at 2^30: tanh(>10) rounds to 1.0f exactly and all
    // products stay < 2^90 (no overflow); negative underflow is exact.
#define LSTM_CELLPAIR(ACC0, ACC1)                                              \
    {                                                                          \
        const float A0 = FAST_EXP2(ACC0[0]), A1 = FAST_EXP2(ACC1[0]);          \
        const float F0 = FAST_EXP2(ACC0[1]), F1 = FAST_EXP2(ACC1[1]);          \
        const float E0 = FAST_EXP2(fminf(ACC0[2], 30.0f));                     \
        const float E1 = FAST_EXP2(fminf(ACC1[2], 30.0f));                     \
        const float P0 = (1.0f + A0) * (E0 + 1.0f), Q0 = 1.0f + F0;            \
        const float P1 = (1.0f + A1) * (E1 + 1.0f), Q1 = 1.0f + F1;            \
        const float PQ0 = P0 * Q0, PQ1 = P1 * Q1;                              \
        const float R = FAST_RCP(PQ0 * PQ1);                                   \
        c0 = (c0 * P0 + (E0 - 1.0f) * Q0) * (R * PQ1);                         \
        c1 = (c1 * P1 + (E1 - 1.0f) * Q1) * (R * PQ0);                         \
        const float O0 = FAST_EXP2(ACC0[3]), O1 = FAST_EXP2(ACC1[3]);          \
        const float C0 = FAST_EXP2(fminf(2.88539008177792681472f * c0, 30.0f));\
        const float C1 = FAST_EXP2(fminf(2.88539008177792681472f * c1, 30.0f));\
        const float d0 = (1.0f + O0) * (C0 + 1.0f);                            \
        const float d1 = (1.0f + O1) * (C1 + 1.0f);                            \
        const float Rh = FAST_RCP(d0 * d1);                                    \
        h0 = (C0 - 1.0f) * (Rh * d1);                                          \
        h1 = (C1 - 1.0f) * (Rh * d0);                                          \
    }

#define LSTM_STEP(TT, RB, HW, XW, XREG)                                        \
    {                                                                          \
        const half8 bf0 = *(const half8*)(RB);                                 \
        const half8 bf1 = *(const half8*)((RB) + 32);                          \
        const half8 bf2 = *(const half8*)((RB) + 64);                          \
        if (xact) {                                                            \
            *(XW) = (_Float16)XREG;                                            \
            int tl = (TT) + 3;                                                 \
            if (tl >= T_STEPS) tl = T_STEPS - 1;                               \
            XREG = xcol[tl * I_DIM];                                           \
        }                                                                      \
        f32x4 acc0 = {0.f, 0.f, 0.f, 0.f};                                     \
        f32x4 acc1 = {0.f, 0.f, 0.f, 0.f};                                     \
        acc0 = __builtin_amdgcn_mfma_f32_16x16x32_f16(afrag[0][0], bf0, acc0, 0, 0, 0); \
        acc1 = __builtin_amdgcn_mfma_f32_16x16x32_f16(afrag[1][0], bf0, acc1, 0, 0, 0); \
        acc0 = __builtin_amdgcn_mfma_f32_16x16x32_f16(afrag[0][1], bf1, acc0, 0, 0, 0); \
        acc1 = __builtin_amdgcn_mfma_f32_16x16x32_f16(afrag[1][1], bf1, acc1, 0, 0, 0); \
        acc0 = __builtin_amdgcn_mfma_f32_16x16x32_f16(afrag[0][2], bf2, acc0, 0, 0, 0); \
        acc1 = __builtin_amdgcn_mfma_f32_16x16x32_f16(afrag[1][2], bf2, acc1, 0, 0, 0); \
        LSTM_CELLPAIR(acc0, acc1)                                              \
        *(HW) = (half2v){(_Float16)h0, (_Float16)h1};                          \
        __syncthreads();                                                       \
    }

    for (int t = 0; t < T_STEPS; t += 2) {
        LSTM_STEP(t, rb0, hw1, xw1, xA)       // read buf0, write buf1
        LSTM_STEP(t + 1, rb1, hw0, xw0, xB)   // read buf1, write buf0
    }
#undef LSTM_STEP
#undef LSTM_CELLPAIR

    // ---- epilogue: out[b][j] = b_fc[j] + sum_u h[b][u] * W_fc[j][u] ----
    *(f32x2*)&hlds[n15][u0] = (f32x2){h0, h1};
    __syncthreads();
    if (tid < 256) {
        const int b = tid >> 4, j = tid & 15;
        float s = b_fc[j];
#pragma unroll 8
        for (int u = 0; u < HDIM; ++u)
            s += hlds[b][u] * W_fc[j * HDIM + u];
        out[(bbase + b) * 16 + j] = s;
    }
}

extern "C" void kernel_launch(void* const* d_in, const int* in_sizes, int n_in,
                              void* d_out, int out_size, void* d_ws, size_t ws_size,
                              hipStream_t stream) {
    const float* x    = (const float*)d_in[0];
    const float* W_ih = (const float*)d_in[1];
    const float* W_hh = (const float*)d_in[2];
    const float* b_ih = (const float*)d_in[3];
    const float* b_hh = (const float*)d_in[4];
    const float* W_fc = (const float*)d_in[5];
    const float* b_fc = (const float*)d_in[6];
    float* out = (float*)d_out;

    const int B = in_sizes[0] / XLEN;   // 8192
    const int grid = B / BT;            // 512 blocks = 2 per CU

    lstm_mfma_kernel<<<grid, 512, 0, stream>>>(x, W_ih, W_hh, b_ih, b_hh,
                                               W_fc, b_fc, out);
}

// Round 11
// 198.243 us; speedup vs baseline: 1.0869x; 1.0869x over previous
//
#include <hip/hip_runtime.h>
#include <math.h>

#ifndef __has_builtin
#define __has_builtin(x) 0
#endif

#if __has_builtin(__builtin_amdgcn_rcpf)
#define FAST_RCP(x) __builtin_amdgcn_rcpf(x)
#else
#define FAST_RCP(x) (1.0f / (x))
#endif

#if __has_builtin(__builtin_amdgcn_exp2f)
#define FAST_EXP2(x) __builtin_amdgcn_exp2f(x)
#else
#define FAST_EXP2(x) exp2f(x)
#endif

typedef _Float16 half8 __attribute__((ext_vector_type(8)));
typedef _Float16 half2v __attribute__((ext_vector_type(2)));
typedef float f32x4 __attribute__((ext_vector_type(4)));
typedef float f32x2 __attribute__((ext_vector_type(2)));

constexpr int T_STEPS  = 180;
constexpr int I_DIM    = 7;
constexpr int XLEN     = T_STEPS * I_DIM;  // 1260
constexpr int HDIM     = 64;
constexpr int BT       = 16;    // batch tile per block
constexpr int BSTRIDE  = 104;   // halfs per B row: 208 B (96 data + 8 pad)

// BEST-KNOWN CONFIG (R6 structure, 139 us steady):
// Block = 512 threads = 8 waves, grid 512 -> 2 independent blocks/CU
// (anti-phased barriers; measured better than 1x1024-thr block (+4%),
// x-preload-to-LDS (+7%), cross-cell merged rcp (+7%), x-duty-spread (+12%),
// and 1-cell/thread at 2x occupancy (+6%)).
// Per step GEMM: gates[256 x 16] = W_aug[256 x 96(f16)] . v[96 x 16(f16)],
//   v = [x_t(7), 1, h_{t-1}(64), pad].
// A rows packed UNIT-MAJOR, adjacent-unit remap: lane (q,n15) of wave w's
// tile pt holds i,f,g,o of unit 8w+2q+pt -> thread's 2 cells are adjacent
// units {8w+2q,+1}: ONE packed b32 h write per step.
// Activation scales folded into weights (exp2-ready pre-activations).
// Cell math: shared-denominator, INDEPENDENT per-cell chains (5 exp2 + 2 rcp
// per cell; merging rcps across cells serializes the chains and regresses).
// x path: waves 0-1 only, coalesced 128-lane dword loads, 2-step-deep
// register pipeline (load at t consumed at t+2 -> HBM latency off barrier).
// cs clamp upper-only: exp2 underflow is exact (h -> -sigmoid(o')).
__global__ __launch_bounds__(512, 4) void lstm_mfma_kernel(
    const float* __restrict__ x,
    const float* __restrict__ W_ih,
    const float* __restrict__ W_hh,
    const float* __restrict__ b_ih,
    const float* __restrict__ b_hh,
    const float* __restrict__ W_fc,
    const float* __restrict__ b_fc,
    float* __restrict__ out) {
    __shared__ alignas(16) _Float16 Blds[2][BT][BSTRIDE];
    __shared__ alignas(16) float hlds[BT][HDIM + 4];   // fp32 h_T for epilogue

    const int tid  = (int)threadIdx.x;
    const int w    = tid >> 6;    // wave 0..7
    const int lane = tid & 63;
    const int q    = lane >> 4;   // quad 0..3
    const int n15  = lane & 15;   // batch col within tile
    const long bbase = (long)blockIdx.x * BT;

    // ---- A fragments, scale-folded, in registers for all 180 steps ----
    half8 afrag[2][3];
#pragma unroll
    for (int pt = 0; pt < 2; ++pt) {
        const int rq   = n15 >> 2;            // row-quad of this packed row
        const int gate = n15 & 3;
        const int unit = 8 * w + 2 * rq + pt; // adjacent-unit remap
        const int grow = gate * HDIM + unit;  // row in PyTorch [4H, *] params
        const float scl = (gate == 2) ? 2.88539008177792681472f
                                      : -1.44269504088896340736f;
#pragma unroll
        for (int kc = 0; kc < 3; ++kc) {
#pragma unroll
            for (int j = 0; j < 8; ++j) {
                const int k = kc * 32 + q * 8 + j;
                float v;
                if (k < I_DIM)            v = W_ih[grow * I_DIM + k];
                else if (k == I_DIM)      v = b_ih[grow] + b_hh[grow];
                else if (k < 8 + HDIM)    v = W_hh[grow * HDIM + (k - 8)];
                else                      v = 0.0f;
                afrag[pt][kc][j] = (_Float16)(scl * v);
            }
        }
    }

    // ---- init both B buffers: bias col = 1, h = 0, pad = 0; buf0 x = x_0 ----
    for (int idx = tid; idx < 2 * BT * BSTRIDE; idx += 512) {
        const int buf = idx / (BT * BSTRIDE);
        const int rem = idx % (BT * BSTRIDE);
        const int n = rem / BSTRIDE, k = rem % BSTRIDE;
        float v = 0.0f;
        if (k == I_DIM)                 v = 1.0f;
        else if (k < I_DIM && buf == 0) v = x[(bbase + n) * XLEN + k];
        Blds[buf][n][k] = (_Float16)v;
    }
    __syncthreads();

    // cell ownership: units u0 = 8w+2q, u0+1 (adjacent), batch n15
    const int u0 = 8 * w + 2 * q;

    // hoisted LDS pointers (loop-invariant)
    const _Float16* const rb0 = &Blds[0][n15][q * 8];
    const _Float16* const rb1 = &Blds[1][n15][q * 8];
    half2v* const hw0 = (half2v*)&Blds[0][n15][8 + u0];
    half2v* const hw1 = (half2v*)&Blds[1][n15][8 + u0];

    // x prefetch lanes: threads 0..127 (waves 0,1), n = tid>>3, i = tid&7.
    // Lane i==7 loads a dup column and stores to a dead pad column.
    const int xn = tid >> 3, xi7 = tid & 7;
    const int xi_ld = (xi7 < I_DIM) ? xi7 : I_DIM - 1;
    const int xi_st = (xi7 < I_DIM) ? xi7 : 96 + (xn & 7);
    const bool xact = (tid < 128);              // wave-uniform
    const float* const xcol = x + (bbase + xn) * XLEN + xi_ld;
    _Float16* const xw0 = &Blds[0][xn][xi_st];
    _Float16* const xw1 = &Blds[1][xn][xi_st];

    // 2-deep x pipeline
    float xA = xact ? xcol[1 * I_DIM] : 0.0f;   // x_1 (written during t=0)
    float xB = xact ? xcol[2 * I_DIM] : 0.0f;   // x_2 (written during t=1)

    float c0 = 0.0f, c1 = 0.0f, h0 = 0.0f, h1 = 0.0f;

    // cell: acc = {i',f',g',o'} exp2-ready.  A=2^i', F=2^f', E=2^g', O=2^o'
    //   c' = (c*P + (E-1)*Q) * rcp(P*Q),  P=(1+A)(E+1), Q=1+F
    //   h  = (C-1) * rcp((1+O)(C+1)),     C=2^(k*c'), upper-clamped only.
#define LSTM_CELL(ACC, CREG, HREG)                                             \
    {                                                                          \
        const float A = FAST_EXP2(ACC[0]);                                     \
        const float F = FAST_EXP2(ACC[1]);                                     \
        const float E = FAST_EXP2(ACC[2]);                                     \
        const float P = (1.0f + A) * (E + 1.0f);                               \
        const float Q = 1.0f + F;                                              \
        const float R = FAST_RCP(P * Q);                                       \
        CREG = (CREG * P + (E - 1.0f) * Q) * R;                                \
        const float O = FAST_EXP2(ACC[3]);                                     \
        const float cs = fminf(2.88539008177792681472f * CREG, 126.0f);        \
        const float C = FAST_EXP2(cs);                                         \
        HREG = (C - 1.0f) * FAST_RCP((1.0f + O) * (C + 1.0f));                 \
    }

#define LSTM_STEP(TT, RB, HW, XW, XREG)                                        \
    {                                                                          \
        const half8 bf0 = *(const half8*)(RB);                                 \
        const half8 bf1 = *(const half8*)((RB) + 32);                          \
        const half8 bf2 = *(const half8*)((RB) + 64);                          \
        if (xact) {                                                            \
            *(XW) = (_Float16)XREG;                                            \
            int tl = (TT) + 3;                                                 \
            if (tl >= T_STEPS) tl = T_STEPS - 1;                               \
            XREG = xcol[tl * I_DIM];                                           \
        }                                                                      \
        f32x4 acc0 = {0.f, 0.f, 0.f, 0.f};                                     \
        f32x4 acc1 = {0.f, 0.f, 0.f, 0.f};                                     \
        acc0 = __builtin_amdgcn_mfma_f32_16x16x32_f16(afrag[0][0], bf0, acc0, 0, 0, 0); \
        acc1 = __builtin_amdgcn_mfma_f32_16x16x32_f16(afrag[1][0], bf0, acc1, 0, 0, 0); \
        acc0 = __builtin_amdgcn_mfma_f32_16x16x32_f16(afrag[0][1], bf1, acc0, 0, 0, 0); \
        acc1 = __builtin_amdgcn_mfma_f32_16x16x32_f16(afrag[1][1], bf1, acc1, 0, 0, 0); \
        acc0 = __builtin_amdgcn_mfma_f32_16x16x32_f16(afrag[0][2], bf2, acc0, 0, 0, 0); \
        acc1 = __builtin_amdgcn_mfma_f32_16x16x32_f16(afrag[1][2], bf2, acc1, 0, 0, 0); \
        LSTM_CELL(acc0, c0, h0)                                                \
        LSTM_CELL(acc1, c1, h1)                                                \
        *(HW) = (half2v){(_Float16)h0, (_Float16)h1};                          \
        __syncthreads();                                                       \
    }

    for (int t = 0; t < T_STEPS; t += 2) {
        LSTM_STEP(t, rb0, hw1, xw1, xA)       // read buf0, write buf1
        LSTM_STEP(t + 1, rb1, hw0, xw0, xB)   // read buf1, write buf0
    }
#undef LSTM_STEP
#undef LSTM_CELL

    // ---- epilogue: out[b][j] = b_fc[j] + sum_u h[b][u] * W_fc[j][u] ----
    *(f32x2*)&hlds[n15][u0] = (f32x2){h0, h1};
    __syncthreads();
    if (tid < 256) {
        const int b = tid >> 4, j = tid & 15;
        float s = b_fc[j];
#pragma unroll 8
        for (int u = 0; u < HDIM; ++u)
            s += hlds[b][u] * W_fc[j * HDIM + u];
        out[(bbase + b) * 16 + j] = s;
    }
}

extern "C" void kernel_launch(void* const* d_in, const int* in_sizes, int n_in,
                              void* d_out, int out_size, void* d_ws, size_t ws_size,
                              hipStream_t stream) {
    const float* x    = (const float*)d_in[0];
    const float* W_ih = (const float*)d_in[1];
    const float* W_hh = (const float*)d_in[2];
    const float* b_ih = (const float*)d_in[3];
    const float* b_hh = (const float*)d_in[4];
    const float* W_fc = (const float*)d_in[5];
    const float* b_fc = (const float*)d_in[6];
    float* out = (float*)d_out;

    const int B = in_sizes[0] / XLEN;   // 8192
    const int grid = B / BT;            // 512 blocks = 2 per CU

    lstm_mfma_kernel<<<grid, 512, 0, stream>>>(x, W_ih, W_hh, b_ih, b_hh,
                                               W_fc, b_fc, out);
}